// Round 5
// baseline (1227.056 us; speedup 1.0000x reference)
//
#include <hip/hip_runtime.h>
#include <math.h>

// B=8, Cin=512, H=W=64, Ci=128, Cq=16, recurrence=2. fp32 in/out.
// 3x3 convs: split-bf16 (Wh*Xh + Wh*Xl + Wl*Xh) via 32x32x16 MFMA.
//   - X pre-split/pre-padded bf16 hi/lo half-row panels, staged via global_load_lds.
//   - W fragments loaded global->VGPR (no LDS), 1-tap software pipeline.
//   - Only 2 barriers per 32-ci chunk (X stage / chunk swap).
// cc module: fp32 vector kernels; softmax fused into ew kernel.

typedef __attribute__((ext_vector_type(8)))  short short8;   // 8 bf16 (4 VGPR)
typedef __attribute__((ext_vector_type(4)))  float f32x4;
typedef __attribute__((ext_vector_type(16))) float f32x16;

__device__ __forceinline__ unsigned short f2bf(float x) {
    unsigned u = __float_as_uint(x);
    unsigned r = u + 0x7FFFu + ((u >> 16) & 1u);
    return (unsigned short)(r >> 16);
}
__device__ __forceinline__ float bf2f(unsigned short h) {
    return __uint_as_float(((unsigned)h) << 16);
}
// packed split: (a,b) -> hi-pair u32, lo-pair u32
__device__ __forceinline__ void split2(float a, float b, unsigned& hi, unsigned& lo) {
    unsigned h;
    asm("v_cvt_pk_bf16_f32 %0, %1, %2" : "=v"(h) : "v"(a), "v"(b));
    float ra = a - __uint_as_float(h << 16);
    float rb = b - __uint_as_float(h & 0xffff0000u);
    unsigned l;
    asm("v_cvt_pk_bf16_f32 %0, %1, %2" : "=v"(l) : "v"(ra), "v"(rb));
    hi = h; lo = l;
}
__device__ __forceinline__ void gll16(const unsigned short* g, unsigned short* l) {
    __builtin_amdgcn_global_load_lds(
        (const __attribute__((address_space(1))) unsigned int*)g,
        (__attribute__((address_space(3))) unsigned int*)l, 16, 0, 0);
}

// ---------------- prep: fold BN into scale/shift ----------------
__global__ __launch_bounds__(256) void prep_bn_kernel(
        const float* g1, const float* b1, const float* m1, const float* v1,
        const float* g2, const float* b2, const float* m2, const float* v2,
        float* s1o, float* h1o, float* s2o, float* h2o) {
    int t = threadIdx.x;
    if (t < 128) {
        float s = g1[t] * __frsqrt_rn(v1[t] + 1e-5f);
        s1o[t] = s; h1o[t] = b1[t] - m1[t] * s;
    } else {
        int c = t - 128;
        float s = g2[c] * __frsqrt_rn(v2[c] + 1e-5f);
        s2o[c] = s; h2o[c] = b2[c] - m2[c] * s;
    }
}

// ---------------- prep: conv weights -> dense bf16 hi/lo planes ----------------
// Wp layout: [ck][tap][hl][COUT][32]  (dense 64B rows)
__global__ __launch_bounds__(256) void prep_w2(
        const float* __restrict__ w, unsigned short* __restrict__ Wp, int CIN, int COUT) {
    int idx = blockIdx.x * 256 + threadIdx.x;
    if (idx >= COUT * CIN) return;
    int cout = idx / CIN, ci = idx - cout * CIN;
    int ck = ci >> 5, cl = ci & 31;
    #pragma unroll
    for (int tap = 0; tap < 9; ++tap) {
        float v = w[(size_t)idx * 9 + tap];
        unsigned short h = f2bf(v);
        unsigned short l = f2bf(v - bf2f(h));
        size_t rb = (((size_t)ck * 9 + tap) * 2 * COUT + cout) * 32;  // hi row
        Wp[rb + cl] = h;
        Wp[rb + (size_t)COUT * 32 + cl] = l;                          // lo plane
    }
}

// ---------------- prep: transpose 1x1-conv weights ----------------
__global__ __launch_bounds__(256) void prep_qkv_kernel(
        const float* __restrict__ wq, const float* __restrict__ wk,
        const float* __restrict__ wv,
        float* __restrict__ wqk_t, float* __restrict__ wv_t) {
    int e = blockIdx.x * 256 + threadIdx.x;
    if (e < 4096) {
        int ci = e >> 5, co = e & 31;
        wqk_t[e] = (co < 16) ? wq[co * 128 + ci] : wk[(co - 16) * 128 + ci];
    } else if (e < 4096 + 16384) {
        int e2 = e - 4096;
        int ci = e2 >> 7, co = e2 & 127;
        wv_t[e2] = wv[co * 128 + ci];
    }
}

// ---------------- NCHW fp32 -> split bf16 hi/lo half-row panels ----------------
// XT per (b,ck,hl): [64 h][2 halves][34 slots][40 shorts]  (PLANE = 64*68*40)
// half0 slots = w -1..32 (slot0 zero halo), half1 slots = w 31..64 (slot33 zero halo).
__global__ __launch_bounds__(256) void transpose_split_kernel(
        const float* __restrict__ in, unsigned short* __restrict__ out, int NCH) {
    __shared__ float T[32][260];
    const int t = threadIdx.x;
    const int h0 = blockIdx.x * 4, b = blockIdx.y, ck = blockIdx.z;
    const float* base = in + (size_t)(b * NCH + ck) * 32 * 4096;
    const int ci = t >> 3, w0 = (t & 7) * 8;
    #pragma unroll
    for (int hh = 0; hh < 4; ++hh) {
        float4 u0 = *(const float4*)&base[(size_t)ci * 4096 + (h0 + hh) * 64 + w0];
        float4 u1 = *(const float4*)&base[(size_t)ci * 4096 + (h0 + hh) * 64 + w0 + 4];
        T[ci][hh * 65 + w0 + 0] = u0.x; T[ci][hh * 65 + w0 + 1] = u0.y;
        T[ci][hh * 65 + w0 + 2] = u0.z; T[ci][hh * 65 + w0 + 3] = u0.w;
        T[ci][hh * 65 + w0 + 4] = u1.x; T[ci][hh * 65 + w0 + 5] = u1.y;
        T[ci][hh * 65 + w0 + 6] = u1.z; T[ci][hh * 65 + w0 + 7] = u1.w;
    }
    __syncthreads();
    const int w = t & 63, hh2 = t >> 6;
    const int h = h0 + hh2;
    const size_t PL = (size_t)64 * 68 * 40;
    unsigned short* po = out + ((size_t)(b * NCH + ck) * 2) * PL;
    unsigned hi[16], lo[16];
    #pragma unroll
    for (int p = 0; p < 16; ++p) {
        float a = T[2 * p][hh2 * 65 + w];
        float c = T[2 * p + 1][hh2 * 65 + w];
        split2(a, c, hi[p], lo[p]);
    }
    uint4 zz = {0u, 0u, 0u, 0u};
    #pragma unroll
    for (int half = 0; half < 2; ++half) {
        bool ok = half ? (w >= 31) : (w <= 32);
        int slot = half ? (w - 31) : (w + 1);
        if (ok) {
            unsigned short* ph = po + ((size_t)h * 68 + half * 34 + slot) * 40;
            unsigned short* pl = ph + PL;
            #pragma unroll
            for (int q = 0; q < 4; ++q) {
                uint4 hv = {hi[q * 4], hi[q * 4 + 1], hi[q * 4 + 2], hi[q * 4 + 3]};
                uint4 lv = {lo[q * 4], lo[q * 4 + 1], lo[q * 4 + 2], lo[q * 4 + 3]};
                *(uint4*)(ph + q * 8) = hv;
                *(uint4*)(pl + q * 8) = lv;
            }
            *(uint4*)(ph + 32) = zz;
            *(uint4*)(pl + 32) = zz;
        }
    }
    if (w == 0 || w == 63) {
        int half = (w == 63);
        int slot = half ? 33 : 0;
        unsigned short* ph = po + ((size_t)h * 68 + half * 34 + slot) * 40;
        #pragma unroll
        for (int q = 0; q < 5; ++q) {
            *(uint4*)(ph + q * 8) = zz;
            *(uint4*)(ph + PL + q * 8) = zz;
        }
    }
}

// ---------------- 3x3 conv: split-bf16 32x32x16 MFMA, W from global ----------------
// Block: 128 threads = 2 waves (ch = cout-half). Wave: m=2 (64 cout) x n=4 (4 rows x 32 w).
// Block output: 128 cout x 4 rows x 32 w. EPI: 0 = BN, 1 = ELU(512).
template<int NCHUNK, int COUT, int EPI, int C1CH>
__global__ __launch_bounds__(128, 2) void conv3x3_g(
        const unsigned short* __restrict__ xt1, const unsigned short* __restrict__ xt2,
        const unsigned short* __restrict__ Wp,
        const float* __restrict__ bns, const float* __restrict__ bnb,
        float* __restrict__ out) {
    __shared__ __align__(16) unsigned short XS[2][6][34][40];   // [hl][row][wslot][ci], 32.6 KB
    const int t = threadIdx.x;
    const int lane = t & 63, ch = t >> 6;         // wave id == cout-half
    const int lw = lane & 31, kg = lane >> 5;
    const int h0 = blockIdx.x * 4;
    const int b  = blockIdx.y;
    const int cz = blockIdx.z >> 1, wz = blockIdx.z & 1;
    const int cb0 = cz * 128;
    const size_t XPLANE = (size_t)64 * 68 * 40;
    constexpr int HLSTR = 6 * 34 * 40;            // XS hi->lo stride in shorts

    const f32x16 fz = {0.f,0.f,0.f,0.f,0.f,0.f,0.f,0.f,0.f,0.f,0.f,0.f,0.f,0.f,0.f,0.f};
    f32x16 acc[2][4];
    #pragma unroll
    for (int mt = 0; mt < 2; ++mt)
        #pragma unroll
        for (int r = 0; r < 4; ++r) acc[mt][r] = fz;

    #pragma unroll 1
    for (int chunk = 0; chunk < NCHUNK; ++chunk) {
        // ---- stage X: wave ch stages its hl plane (6 rows x 170 16B-units) ----
        const unsigned short* xb = (chunk < C1CH)
            ? xt1 + ((size_t)(b * C1CH + chunk) * 2) * XPLANE
            : xt2 + ((size_t)(b * (NCHUNK - C1CH) + (chunk - C1CH)) * 2) * XPLANE;
        #pragma unroll
        for (int j = 0; j < 6; ++j) {
            const int grow = h0 - 1 + j;
            unsigned short* ld = &XS[ch][j][0][0];
            if (grow >= 0 && grow < 64) {
                const unsigned short* g = xb + (size_t)ch * XPLANE + ((size_t)grow * 68 + wz * 34) * 40;
                gll16(g + (size_t)lane * 8, ld + (size_t)lane * 8);
                gll16(g + (size_t)(64 + lane) * 8, ld + (size_t)(64 + lane) * 8);
                if (lane < 42)
                    gll16(g + (size_t)(128 + lane) * 8, ld + (size_t)(128 + lane) * 8);
            } else {
                short8 z = {};
                *(short8*)(ld + (size_t)lane * 8) = z;
                *(short8*)(ld + (size_t)(64 + lane) * 8) = z;
                if (lane < 42) *(short8*)(ld + (size_t)(128 + lane) * 8) = z;
            }
        }
        __syncthreads();   // (compiler drains vmcnt before s_barrier)

        // ---- W fragment loads: global->VGPR, 1-tap pipeline ----
        const unsigned short* wbase = Wp + (size_t)chunk * (9 * 2 * (size_t)COUT * 32);
        const int crow = cb0 + ch * 64 + lw;
        short8 wc[8], wn[8];
        {   // preload tap 0
            const unsigned short* ph = wbase + ((size_t)0 * COUT + crow) * 32 + kg * 8;
            const unsigned short* pl = ph + (size_t)COUT * 32;
            wc[0] = *(const short8*)(ph);             wc[1] = *(const short8*)(ph + 32 * 32);
            wc[2] = *(const short8*)(pl);             wc[3] = *(const short8*)(pl + 32 * 32);
            wc[4] = *(const short8*)(ph + 16);        wc[5] = *(const short8*)(ph + 32 * 32 + 16);
            wc[6] = *(const short8*)(pl + 16);        wc[7] = *(const short8*)(pl + 32 * 32 + 16);
        }
        #pragma unroll 1
        for (int tap = 0; tap < 9; ++tap) {
            {   // prefetch next tap (tap 8 harmlessly re-reads tap 0)
                const int tn = (tap < 8) ? tap + 1 : 0;
                const unsigned short* ph = wbase + ((size_t)(tn * 2) * COUT + crow) * 32 + kg * 8;
                const unsigned short* pl = ph + (size_t)COUT * 32;
                wn[0] = *(const short8*)(ph);         wn[1] = *(const short8*)(ph + 32 * 32);
                wn[2] = *(const short8*)(pl);         wn[3] = *(const short8*)(pl + 32 * 32);
                wn[4] = *(const short8*)(ph + 16);    wn[5] = *(const short8*)(ph + 32 * 32 + 16);
                wn[6] = *(const short8*)(pl + 16);    wn[7] = *(const short8*)(pl + 32 * 32 + 16);
            }
            const int kh = (tap < 3) ? 0 : ((tap < 6) ? 1 : 2);
            const int kw = tap - kh * 3;
            #pragma unroll
            for (int ks = 0; ks < 2; ++ks) {
                const short8 ah0 = wc[ks * 4 + 0], ah1 = wc[ks * 4 + 1];
                const short8 al0 = wc[ks * 4 + 2], al1 = wc[ks * 4 + 3];
                const int ko = ks * 16 + kg * 8;
                #pragma unroll
                for (int r = 0; r < 4; ++r) {
                    const unsigned short* xp = &XS[0][r + kh][lw + kw][ko];
                    short8 bh = *(const short8*)xp;
                    short8 bl = *(const short8*)(xp + HLSTR);
                    acc[0][r] = __builtin_amdgcn_mfma_f32_32x32x16_bf16(ah0, bh, acc[0][r], 0, 0, 0);
                    acc[1][r] = __builtin_amdgcn_mfma_f32_32x32x16_bf16(ah1, bh, acc[1][r], 0, 0, 0);
                    acc[0][r] = __builtin_amdgcn_mfma_f32_32x32x16_bf16(ah0, bl, acc[0][r], 0, 0, 0);
                    acc[1][r] = __builtin_amdgcn_mfma_f32_32x32x16_bf16(ah1, bl, acc[1][r], 0, 0, 0);
                    acc[0][r] = __builtin_amdgcn_mfma_f32_32x32x16_bf16(al0, bh, acc[0][r], 0, 0, 0);
                    acc[1][r] = __builtin_amdgcn_mfma_f32_32x32x16_bf16(al1, bh, acc[1][r], 0, 0, 0);
                }
            }
            #pragma unroll
            for (int i = 0; i < 8; ++i) wc[i] = wn[i];
        }
        __syncthreads();   // protect XS before next chunk's staging
    }
    // epilogue: C col = lane&31 -> w, row = (reg&3)+8*(reg>>2)+4*(lane>>5) -> cout
    #pragma unroll
    for (int mt = 0; mt < 2; ++mt) {
        #pragma unroll
        for (int r = 0; r < 4; ++r) {
            const int orow = h0 + r;
            #pragma unroll
            for (int reg = 0; reg < 16; ++reg) {
                const int m = (reg & 3) + 8 * (reg >> 2) + 4 * kg;
                const int cout = cb0 + ch * 64 + mt * 32 + m;
                float val = acc[mt][r][reg];
                if (EPI == 0) val = val * bns[cout] + bnb[cout];
                else          val = (val > 0.f) ? val : 512.0f * expm1f(val);
                out[((size_t)(b * COUT + cout) * 64 + orow) * 64 + wz * 32 + lw] = val;
            }
        }
    }
}

// ================= cc_module kernels (fp32 vector) =================
__global__ __launch_bounds__(256) void qk_kernel(
        const float* __restrict__ X, const float* __restrict__ wqk_t,
        const float* __restrict__ bq, const float* __restrict__ bk,
        float* __restrict__ q, float* __restrict__ k) {
    __shared__ float xls[128][64];
    __shared__ float wls[128][32];
    const int t = threadIdx.x;
    const int h = blockIdx.x, b = blockIdx.y;
    const float* xb = X + (size_t)b * 128 * 4096 + (size_t)h * 64;
    #pragma unroll
    for (int i = 0; i < 32; ++i) {
        int e = t + i * 256;
        xls[e >> 6][e & 63] = xb[(size_t)(e >> 6) * 4096 + (e & 63)];
    }
    #pragma unroll
    for (int i = 0; i < 16; ++i) {
        int e = t + i * 256;
        wls[e >> 5][e & 31] = wqk_t[e];
    }
    __syncthreads();
    const int w = t & 63, g = t >> 6;
    const int co0 = g * 8;
    float acc[8];
    #pragma unroll
    for (int c = 0; c < 8; ++c) acc[c] = 0.f;
    #pragma unroll 8
    for (int ci = 0; ci < 128; ++ci) {
        float xv = xls[ci][w];
        float4 wa = *(const float4*)&wls[ci][co0];
        float4 wb = *(const float4*)&wls[ci][co0 + 4];
        const float* pa = (const float*)&wa;
        const float* pb = (const float*)&wb;
        #pragma unroll
        for (int c = 0; c < 4; ++c) { acc[c] += pa[c] * xv; acc[4 + c] += pb[c] * xv; }
    }
    #pragma unroll
    for (int c = 0; c < 8; ++c) {
        int co = co0 + c;
        if (co < 16) q[((size_t)(b * 16 + co) * 64 + h) * 64 + w]      = acc[c] + bq[co];
        else         k[((size_t)(b * 16 + co - 16) * 64 + h) * 64 + w] = acc[c] + bk[co - 16];
    }
}

__global__ __launch_bounds__(256) void v_kernel(
        const float* __restrict__ X, const float* __restrict__ wv_t,
        const float* __restrict__ bv, float* __restrict__ v) {
    __shared__ float xls[16][64];
    __shared__ float wls[16][128];
    const int t = threadIdx.x;
    const int n0 = blockIdx.x * 64, b = blockIdx.y;
    const int wt = t & 15, ct = t >> 4;
    const float* xb = X + (size_t)b * 128 * 4096;
    float acc[8][4] = {};
    for (int ci0 = 0; ci0 < 128; ci0 += 16) {
        #pragma unroll
        for (int i = 0; i < 4; ++i) {
            int e = t + i * 256;
            xls[e >> 6][e & 63] = xb[(size_t)(ci0 + (e >> 6)) * 4096 + n0 + (e & 63)];
        }
        #pragma unroll
        for (int i = 0; i < 8; ++i) {
            int e = t + i * 256;
            wls[e >> 7][e & 127] = wv_t[(size_t)(ci0 + (e >> 7)) * 128 + (e & 127)];
        }
        __syncthreads();
        #pragma unroll 4
        for (int ci = 0; ci < 16; ++ci) {
            float4 xv = *(const float4*)&xls[ci][wt * 4];
            float4 wa = *(const float4*)&wls[ci][ct * 8];
            float4 wb = *(const float4*)&wls[ci][ct * 8 + 4];
            const float* px = (const float*)&xv;
            const float* pa = (const float*)&wa;
            const float* pb = (const float*)&wb;
            #pragma unroll
            for (int j = 0; j < 4; ++j)
                #pragma unroll
                for (int c = 0; c < 4; ++c) {
                    acc[c][j]     += pa[c] * px[j];
                    acc[4 + c][j] += pb[c] * px[j];
                }
        }
        __syncthreads();
    }
    #pragma unroll
    for (int c = 0; c < 8; ++c) {
        int co = ct * 8 + c;
        float bb = bv[co];
        float4 r = {acc[c][0] + bb, acc[c][1] + bb, acc[c][2] + bb, acc[c][3] + bb};
        *(float4*)&v[(size_t)(b * 128 + co) * 4096 + n0 + wt * 4] = r;
    }
}

__global__ __launch_bounds__(256) void eh_kernel(
        const float* __restrict__ q, const float* __restrict__ k,
        float* __restrict__ att) {
    __shared__ float qs[16][64];
    __shared__ float ks[16][64];
    const int t = threadIdx.x;
    const int w = blockIdx.x, b = blockIdx.y;
    #pragma unroll
    for (int i = 0; i < 4; ++i) {
        int e = t + i * 256;
        int c = e >> 6, h = e & 63;
        size_t idx = ((size_t)(b * 16 + c) * 64 + h) * 64 + w;
        qs[c][h] = q[idx];
        ks[c][h] = k[idx];
    }
    __syncthreads();
    const int g0 = (t & 15) * 4, h0 = (t >> 4) * 4;
    float acc[4][4] = {};
    #pragma unroll
    for (int c = 0; c < 16; ++c) {
        float4 qv = *(const float4*)&qs[c][h0];
        float4 kv = *(const float4*)&ks[c][g0];
        const float* pq = (const float*)&qv;
        const float* pk = (const float*)&kv;
        #pragma unroll
        for (int i = 0; i < 4; ++i)
            #pragma unroll
            for (int j = 0; j < 4; ++j) acc[i][j] += pq[i] * pk[j];
    }
    #pragma unroll
    for (int i = 0; i < 4; ++i) {
        int h = h0 + i;
        int dj = h - g0;
        if (dj >= 0 && dj < 4) acc[i][dj] = -1e30f;
        float4 r = {acc[i][0], acc[i][1], acc[i][2], acc[i][3]};
        *(float4*)&att[((size_t)(b * 64 + h) * 64 + w) * 128 + g0] = r;
    }
}

// ---------------- eW scores + full-row softmax (fused) ----------------
// Block (b,h): computes eW half, loads eH half (written by eh_kernel),
// softmaxes the 128-logit rows in LDS, writes normalized att.
__global__ __launch_bounds__(256) void ew_softmax_kernel(
        const float* __restrict__ q, const float* __restrict__ k,
        float* __restrict__ att) {
    __shared__ float qs[16][64];
    __shared__ float ks[16][64];
    __shared__ float ehs[64][65];
    __shared__ float ews[64][65];
    __shared__ float sinv[64];
    const int t = threadIdx.x;
    const int h = blockIdx.x, b = blockIdx.y;
    const float* qb2 = q + (size_t)b * 65536 + (size_t)h * 64;
    const float* kb2 = k + (size_t)b * 65536 + (size_t)h * 64;
    #pragma unroll
    for (int i = 0; i < 4; ++i) {
        int e = t + i * 256;
        int c = e >> 6, wl = e & 63;
        qs[c][wl] = qb2[(size_t)c * 4096 + wl];
        ks[c][wl] = kb2[(size_t)c * 4096 + wl];
    }
    float* abase = att + (size_t)(b * 64 + h) * 64 * 128;
    #pragma unroll
    for (int i = 0; i < 16; ++i) {
        int e = t + i * 256;
        ehs[e >> 6][e & 63] = abase[(size_t)(e >> 6) * 128 + (e & 63)];
    }
    __syncthreads();
    const int tt0 = (t & 15) * 4, w0 = (t >> 4) * 4;
    float acc[4][4] = {};
    #pragma unroll
    for (int c = 0; c < 16; ++c) {
        float4 qv = *(const float4*)&qs[c][w0];
        float4 kv = *(const float4*)&ks[c][tt0];
        const float* pq = (const float*)&qv;
        const float* pk = (const float*)&kv;
        #pragma unroll
        for (int i = 0; i < 4; ++i)
            #pragma unroll
            for (int j = 0; j < 4; ++j) acc[i][j] += pq[i] * pk[j];
    }
    #pragma unroll
    for (int i = 0; i < 4; ++i)
        #pragma unroll
        for (int j = 0; j < 4; ++j) ews[w0 + i][tt0 + j] = acc[i][j];
    __syncthreads();
    // softmax: 4 threads per row; qd 0..1 scan eH, 2..3 scan eW
    const int r = t >> 2, qd = t & 3;
    float* src = (qd < 2) ? &ehs[r][qd * 32] : &ews[r][(qd - 2) * 32];
    float m = -3.0e38f;
    #pragma unroll
    for (int kk = 0; kk < 32; ++kk) m = fmaxf(m, src[kk]);
    m = fmaxf(m, __shfl_xor(m, 1));
    m = fmaxf(m, __shfl_xor(m, 2));
    float s = 0.f;
    #pragma unroll
    for (int kk = 0; kk < 32; ++kk) {
        float e = expf(src[kk] - m);
        src[kk] = e;
        s += e;
    }
    s += __shfl_xor(s, 1);
    s += __shfl_xor(s, 2);
    if (qd == 0) sinv[r] = 1.0f / s;
    __syncthreads();
    #pragma unroll
    for (int i = 0; i < 32; ++i) {
        int e = t + i * 256;
        int row = e >> 7, col = e & 127;
        float vsm = (col < 64) ? ehs[row][col] : ews[row][col - 64];
        abase[(size_t)row * 128 + col] = vsm * sinv[row];
    }
}

__global__ __launch_bounds__(256) void oh_kernel(
        const float* __restrict__ v, const float* __restrict__ att,
        float* __restrict__ ohb) {
    __shared__ float vs2[64][128];
    __shared__ float ah2[64][65];
    const int t = threadIdx.x;
    const int w = blockIdx.x, b = blockIdx.y;
    const float* vbp = v + (size_t)b * 524288 + w;
    #pragma unroll
    for (int i = 0; i < 32; ++i) {
        int e = t + i * 256;
        vs2[e >> 7][e & 127] = vbp[((size_t)(e & 127) * 64 + (e >> 7)) * 64];
    }
    const float* abp = att + ((size_t)b * 4096 + w) * 128;
    #pragma unroll
    for (int i = 0; i < 16; ++i) {
        int e = t + i * 256;
        ah2[e >> 6][e & 63] = abp[(size_t)(e >> 6) * 8192 + (e & 63)];
    }
    __syncthreads();
    const int h0 = (t & 15) * 4, c0 = (t >> 4) * 8;
    float acc[8][4] = {};
    for (int g = 0; g < 64; ++g) {
        float4 va  = *(const float4*)&vs2[g][c0];
        float4 vb4 = *(const float4*)&vs2[g][c0 + 4];
        const float* pa = (const float*)&va;
        const float* pb = (const float*)&vb4;
        float aj[4];
        #pragma unroll
        for (int j = 0; j < 4; ++j) aj[j] = ah2[h0 + j][g];
        #pragma unroll
        for (int j = 0; j < 4; ++j)
            #pragma unroll
            for (int i2 = 0; i2 < 4; ++i2) {
                acc[i2][j]     += pa[i2] * aj[j];
                acc[4 + i2][j] += pb[i2] * aj[j];
            }
    }
    #pragma unroll
    for (int i2 = 0; i2 < 8; ++i2)
        #pragma unroll
        for (int j = 0; j < 4; ++j)
            ohb[((size_t)(b * 128 + c0 + i2) * 64 + (h0 + j)) * 64 + w] = acc[i2][j];
}

__global__ __launch_bounds__(256) void ow_final_kernel(
        const float* __restrict__ v, const float* __restrict__ att,
        const float* __restrict__ ohb, const float* __restrict__ gamma,
        const float* __restrict__ Xin, float* __restrict__ Xout) {
    __shared__ float vs2[64][129];
    __shared__ float aws[64][65];
    const int t = threadIdx.x;
    const int h = blockIdx.x, b = blockIdx.y;
    const float* vbp = v + (size_t)b * 524288 + (size_t)h * 64;
    #pragma unroll
    for (int i = 0; i < 32; ++i) {
        int e = t + i * 256;
        vs2[e & 63][e >> 6] = vbp[(size_t)(e >> 6) * 4096 + (e & 63)];
    }
    const float* abp = att + ((size_t)(b * 64 + h) * 64) * 128 + 64;
    #pragma unroll
    for (int i = 0; i < 16; ++i) {
        int e = t + i * 256;
        aws[e >> 6][e & 63] = abp[(size_t)(e >> 6) * 128 + (e & 63)];
    }
    __syncthreads();
    const int w0 = (t & 15) * 4, c0 = (t >> 4) * 8;
    float acc[8][4] = {};
    for (int tt = 0; tt < 64; ++tt) {
        float vv[8];
        #pragma unroll
        for (int i2 = 0; i2 < 8; ++i2) vv[i2] = vs2[tt][c0 + i2];
        float aw[4];
        #pragma unroll
        for (int j = 0; j < 4; ++j) aw[j] = aws[w0 + j][tt];
        #pragma unroll
        for (int i2 = 0; i2 < 8; ++i2)
            #pragma unroll
            for (int j = 0; j < 4; ++j) acc[i2][j] += vv[i2] * aw[j];
    }
    const float gm = gamma[0];
    #pragma unroll
    for (int i2 = 0; i2 < 8; ++i2) {
        size_t base = ((size_t)(b * 128 + c0 + i2) * 64 + h) * 64 + w0;
        float4 oh4 = *(const float4*)&ohb[base];
        float4 xr  = *(const float4*)&Xin[base];
        const float* po = (const float*)&oh4;
        const float* px = (const float*)&xr;
        float4 r;
        float* pr = (float*)&r;
        #pragma unroll
        for (int j = 0; j < 4; ++j) pr[j] = gm * (acc[i2][j] + po[j]) + px[j];
        *(float4*)&Xout[base] = r;
    }
}

// ---------------- launcher ----------------
extern "C" void kernel_launch(void* const* d_in, const int* in_sizes, int n_in,
                              void* d_out, int out_size, void* d_ws, size_t ws_size,
                              hipStream_t stream) {
    const float* x       = (const float*)d_in[0];
    const float* conva_w = (const float*)d_in[1];
    const float* bn1_g   = (const float*)d_in[2];
    const float* bn1_b   = (const float*)d_in[3];
    const float* bn1_m   = (const float*)d_in[4];
    const float* bn1_v   = (const float*)d_in[5];
    const float* wq      = (const float*)d_in[6];
    const float* bq      = (const float*)d_in[7];
    const float* wk      = (const float*)d_in[8];
    const float* bk      = (const float*)d_in[9];
    const float* wv      = (const float*)d_in[10];
    const float* bv      = (const float*)d_in[11];
    const float* gamma   = (const float*)d_in[12];
    const float* convb_w = (const float*)d_in[13];
    const float* bn2_g   = (const float*)d_in[14];
    const float* bn2_b   = (const float*)d_in[15];
    const float* bn2_m   = (const float*)d_in[16];
    const float* bn2_v   = (const float*)d_in[17];
    const float* bott_w  = (const float*)d_in[18];
    // d_in[19] = recurrence (=2), unrolled on host (graph capture)

    float* ws   = (float*)d_ws;
    float* A    = ws;                        // (8,128,64,64)
    float* Bb   = A    + 4194304;
    float* vbuf = Bb   + 4194304;
    float* attb = vbuf + 4194304;
    float* ohb  = attb + 4194304;
    float* qb   = ohb  + 4194304;
    float* kb   = qb   + 524288;
    unsigned short* XT_x = (unsigned short*)(kb + 524288);   // 44,564,480 shorts
    float* after_xt = kb + 524288 + 22282240;
    unsigned short* Wp_a = (unsigned short*)after_xt;        // 16*9*2*128*32 = 1,179,648 shorts
    unsigned short* Wp_b = Wp_a + 1179648;                   // 4*9*2*128*32  = 294,912
    unsigned short* Wp_c = Wp_b + 294912;                    // 20*9*2*512*32 = 5,898,240
    float* wqk_t = (float*)(Wp_c + 5898240);
    float* wv_t  = wqk_t + 4096;
    float* bnsA  = wv_t + 16384;
    float* bnbA  = bnsA + 128;
    float* bnsB  = bnbA + 128;
    float* bnbB  = bnsB + 128;
    // cc-dead regions reused for the late transposes:
    unsigned short* XT_cc = (unsigned short*)vbuf;            // 11,141,120 shorts
    unsigned short* XT_b  = XT_cc + 11141120;                 // same size (ends inside ohb)

    prep_bn_kernel<<<1, 256, 0, stream>>>(bn1_g, bn1_b, bn1_m, bn1_v,
                                          bn2_g, bn2_b, bn2_m, bn2_v,
                                          bnsA, bnbA, bnsB, bnbB);
    prep_w2<<<256, 256, 0, stream>>>(conva_w, Wp_a, 512, 128);
    prep_w2<<<64, 256, 0, stream>>>(convb_w, Wp_b, 128, 128);
    prep_w2<<<1280, 256, 0, stream>>>(bott_w, Wp_c, 640, 512);
    prep_qkv_kernel<<<80, 256, 0, stream>>>(wq, wk, wv, wqk_t, wv_t);

    transpose_split_kernel<<<dim3(16, 8, 16), 256, 0, stream>>>(x, XT_x, 16);

    conv3x3_g<16, 128, 0, 16><<<dim3(16, 8, 2), 128, 0, stream>>>(
        XT_x, nullptr, Wp_a, bnsA, bnbA, A);

    float* Xi = A;
    float* Xo = Bb;
    for (int it = 0; it < 2; ++it) {   // recurrence = 2
        qk_kernel<<<dim3(64, 8), 256, 0, stream>>>(Xi, wqk_t, bq, bk, qb, kb);
        v_kernel<<<dim3(64, 8), 256, 0, stream>>>(Xi, wv_t, bv, vbuf);
        eh_kernel<<<dim3(64, 8), 256, 0, stream>>>(qb, kb, attb);
        ew_softmax_kernel<<<dim3(64, 8), 256, 0, stream>>>(qb, kb, attb);
        oh_kernel<<<dim3(64, 8), 256, 0, stream>>>(vbuf, attb, ohb);
        ow_final_kernel<<<dim3(64, 8), 256, 0, stream>>>(vbuf, attb, ohb, gamma, Xi, Xo);
        float* tmp = Xi; Xi = Xo; Xo = tmp;
    }
    // Xi == A holds cc output; vbuf/attb/ohb now dead -> XT_cc/XT_b live there

    transpose_split_kernel<<<dim3(16, 8, 4), 256, 0, stream>>>(Xi, XT_cc, 4);
    conv3x3_g<4, 128, 0, 4><<<dim3(16, 8, 2), 128, 0, stream>>>(
        XT_cc, nullptr, Wp_b, bnsB, bnbB, Bb);

    transpose_split_kernel<<<dim3(16, 8, 4), 256, 0, stream>>>(Bb, XT_b, 4);
    conv3x3_g<20, 512, 1, 16><<<dim3(16, 8, 8), 128, 0, stream>>>(
        XT_x, XT_b, Wp_c, nullptr, nullptr, (float*)d_out);
}